// Round 5
// baseline (318.969 us; speedup 1.0000x reference)
//
#include <hip/hip_runtime.h>
#include <stdint.h>

#define NN   2048
#define DD   128
#define DIN  256
#define ROWZ 75

typedef float f32x4 __attribute__((ext_vector_type(4)));
typedef short bf16x8 __attribute__((ext_vector_type(8)));
typedef int   i32x2  __attribute__((ext_vector_type(2)));
typedef unsigned int u32x2 __attribute__((ext_vector_type(2)));

__device__ __forceinline__ unsigned short f2bf(float x){
  union { float f; unsigned int u; } v; v.f = x;
  unsigned int u = v.u;
  u += 0x7fffu + ((u >> 16) & 1u);   // RNE
  return (unsigned short)(u >> 16);
}

// ---------------------------------------------------------------------------
// Kernel A: Wh = h @ W (fp32), row L2 norms.  (unchanged from R7)
// batch = bid&7 so the XCD that WRITES batch b's whn/whT is the XCD that
// READS it in attn (round-robin dispatch: XCD = bid%8).
// ---------------------------------------------------------------------------
__launch_bounds__(256, 2)
__global__ void wh_kernel(const float* __restrict__ h, const float* __restrict__ W,
                          unsigned short* __restrict__ whn, unsigned short* __restrict__ whT)
{
  __shared__ float hs[32][36];
  __shared__ float Ws[32][128];
  __shared__ float ssp[32][33];
  __shared__ float sinv[32];

  const int t  = threadIdx.x;
  const int bid = blockIdx.x;
  const int r0 = ((bid & 7) << 11) | ((bid >> 3) << 5);   // batch=bid&7
  const int r4 = (t >> 5) * 4;
  const int d4 = (t & 31) * 4;

  float acc[4][4];
#pragma unroll
  for (int i = 0; i < 4; ++i)
#pragma unroll
    for (int j = 0; j < 4; ++j) acc[i][j] = 0.f;

  const int lrow = t >> 3;
  const int lkb  = (t & 7) * 4;
  const int wk   = t >> 3;
  const int wd   = (t & 7) * 16;

  f32x4 ph = *(const f32x4*)(h + (size_t)(r0 + lrow) * DIN + lkb);
  f32x4 pW[4];
  {
    const float* ws = W + (size_t)wk * DD + wd;
#pragma unroll
    for (int e = 0; e < 4; ++e) pW[e] = ((const f32x4*)ws)[e];
  }

  for (int kt = 0; kt < 8; ++kt){
    __syncthreads();
#pragma unroll
    for (int e = 0; e < 4; ++e) hs[lkb + e][lrow] = ph[e];
    {
      f32x4* dst = (f32x4*)&Ws[wk][wd];
#pragma unroll
      for (int e = 0; e < 4; ++e) dst[e] = pW[e];
    }
    __syncthreads();

    if (kt < 7){
      ph = *(const f32x4*)(h + (size_t)(r0 + lrow) * DIN + (kt+1)*32 + lkb);
      const float* ws = W + (size_t)((kt+1)*32 + wk) * DD + wd;
#pragma unroll
      for (int e = 0; e < 4; ++e) pW[e] = ((const f32x4*)ws)[e];
    }

#pragma unroll
    for (int k = 0; k < 32; ++k){
      f32x4 w4 = *(const f32x4*)&Ws[k][d4];
      f32x4 ha = *(const f32x4*)&hs[k][r4];
#pragma unroll
      for (int i = 0; i < 4; ++i)
#pragma unroll
        for (int j = 0; j < 4; ++j)
          acc[i][j] += ha[i] * w4[j];
    }
  }

#pragma unroll
  for (int i = 0; i < 4; ++i){
    float s = acc[i][0]*acc[i][0] + acc[i][1]*acc[i][1]
            + acc[i][2]*acc[i][2] + acc[i][3]*acc[i][3];
    ssp[r4 + i][t & 31] = s;
  }
  __syncthreads();
  if (t < 32){
    float ss = 0.f;
#pragma unroll
    for (int c = 0; c < 32; ++c) ss += ssp[t][c];
    sinv[t] = 1.0f / fmaxf(sqrtf(ss), 1e-12f);
  }
  __syncthreads();

  const int bb = r0 >> 11;
  const int n0 = (r0 & 2047) + r4;

#pragma unroll
  for (int i = 0; i < 4; ++i){
    const float inv = sinv[r4 + i];
    unsigned int lo = (unsigned int)f2bf(acc[i][0]*inv) | ((unsigned int)f2bf(acc[i][1]*inv) << 16);
    unsigned int hi = (unsigned int)f2bf(acc[i][2]*inv) | ((unsigned int)f2bf(acc[i][3]*inv) << 16);
    u32x2 pk = { lo, hi };
    *(u32x2*)(whn + (size_t)(r0 + r4 + i) * DD + d4) = pk;
  }
#pragma unroll
  for (int j = 0; j < 4; ++j){
    u32x2 pk;
#pragma unroll
    for (int e = 0; e < 2; ++e)
      pk[e] = (unsigned int)f2bf(acc[2*e][j]) | ((unsigned int)f2bf(acc[2*e + 1][j]) << 16);
    *(u32x2*)(whT + ((size_t)(bb * DD + d4 + j)) * NN + n0) = pk;
  }
}

// ---------------------------------------------------------------------------
// Kernel B (R8): barrier-free K-loop. K and V fragments loaded DIRECTLY from
// global (XCD-pinned batch slice = 0.5 MB each, L2-resident — staging them in
// LDS was pure overhead at 1 block/CU). P stays wave-private in LDS (20 KB).
// Even/odd m-permutation: lane's two fragments = m-rows {2*l16, 2*l16+1}
//   -> adj loads halve (8x dwordx2), P writes halve (8x u32), coalescing
//   unchanged (16x64B segments/instr). Permutation applied consistently to
//   kf rows + adj cols + P write cols; PV consumes natural column order.
// No __syncthreads in the loop at all: waves self-stagger (latency hiding).
// ---------------------------------------------------------------------------
__launch_bounds__(512, 2)
__global__ void attn_kernel(const unsigned short* __restrict__ whn,
                            const unsigned short* __restrict__ whT,
                            const int* __restrict__ adje,
                            float* __restrict__ out)
{
  __shared__ float smem[16384];     // 64 KB union: Pbuf(20KB)+fl(16KB) in-loop / owf epilogue
  __shared__ float linv_s[64];

  const int t    = threadIdx.x;
  const int w    = t >> 6;
  const int l    = t & 63;
  const int quad = l >> 4;
  const int l16  = l & 15;
  const int qh   = w >> 2;            // q-half 0/1
  const int ms   = w & 3;             // m-strip 0..3
  const int b     = blockIdx.x & 7;   // XCD-pinned batch (round-robin dispatch)
  const int qbase = (blockIdx.x >> 3) * 64;

  const unsigned short* whn_b = whn + (size_t)b * NN * DD;
  const unsigned short* whT_b = whT + (size_t)b * DD * NN;
  const int*            adj_b = adje + (size_t)b * NN * NN;

  unsigned short* const Pw = (unsigned short*)smem + w * (32 * 40);

  // Q fragments: rows qbase + qh*32 + s*16 + l16
  bf16x8 qf[2][4];
#pragma unroll
  for (int s = 0; s < 2; ++s)
#pragma unroll
    for (int kc = 0; kc < 4; ++kc)
      qf[s][kc] = *(const bf16x8*)(whn_b + (size_t)(qbase + qh*32 + s*16 + l16) * DD + kc*32 + quad*8);

  f32x4 oacc[2][8];
  float lacc[2][4];
#pragma unroll
  for (int s = 0; s < 2; ++s){
#pragma unroll
    for (int dt = 0; dt < 8; ++dt) oacc[s][dt] = (f32x4){0.f, 0.f, 0.f, 0.f};
#pragma unroll
    for (int r = 0; r < 4; ++r) lacc[s][r] = 0.f;
  }

  // row-zeroing-bug predicate, hoisted (loop-invariant)
  bool zr[2][4];
#pragma unroll
  for (int s = 0; s < 2; ++s)
#pragma unroll
    for (int r = 0; r < 4; ++r)
      zr[s][r] = (qbase + qh*32 + s*16 + quad*4 + r) < ROWZ;

  // prologue: adj pair-loads for it=0 (cols 2*l16, 2*l16+1 of this wave's strip)
  i32x2 av[2][4];
#pragma unroll
  for (int s = 0; s < 2; ++s)
#pragma unroll
    for (int r = 0; r < 4; ++r)
      av[s][r] = *(const i32x2*)(adj_b + (size_t)(qbase + qh*32 + s*16 + quad*4 + r) * NN + ms*32 + 2*l16);

  for (int it = 0; it < 16; ++it){
    const int m0 = it * 128;

    // ---- K fragments direct from global (L2): rows m0+ms*32+2*l16+f ----
    bf16x8 kf[2][4];
#pragma unroll
    for (int f = 0; f < 2; ++f)
#pragma unroll
      for (int kc = 0; kc < 4; ++kc)
        kf[f][kc] = *(const bf16x8*)(whn_b + (size_t)(m0 + ms*32 + 2*l16 + f) * DD + kc*32 + quad*8);

    // ---- adj prefetch for it+1 (HBM, a full iteration to land) ----
    i32x2 avn[2][4];
    if (it < 15){
      const int mn = m0 + 128;
#pragma unroll
      for (int s = 0; s < 2; ++s)
#pragma unroll
        for (int r = 0; r < 4; ++r)
          avn[s][r] = *(const i32x2*)(adj_b + (size_t)(qbase + qh*32 + s*16 + quad*4 + r) * NN + mn + ms*32 + 2*l16);
    }

    // ---- QK + mask + exp -> packed P (u32 = 2 adjacent m-cols) ----
#pragma unroll
    for (int s = 0; s < 2; ++s){
      f32x4 sc0 = (f32x4){0.f,0.f,0.f,0.f};
      f32x4 sc1 = (f32x4){0.f,0.f,0.f,0.f};
#pragma unroll
      for (int kc = 0; kc < 4; ++kc){
        sc0 = __builtin_amdgcn_mfma_f32_16x16x32_bf16(qf[s][kc], kf[0][kc], sc0, 0, 0, 0);
        sc1 = __builtin_amdgcn_mfma_f32_16x16x32_bf16(qf[s][kc], kf[1][kc], sc1, 0, 0, 0);
      }
#pragma unroll
      for (int r = 0; r < 4; ++r){
        float sv0 = zr[s][r] ? 0.f : sc0[r];
        float sv1 = zr[s][r] ? 0.f : sc1[r];
        float p0 = (av[s][r].x > 0) ? __expf(sv0) : 0.f;
        float p1 = (av[s][r].y > 0) ? __expf(sv1) : 0.f;
        lacc[s][r] += p0 + p1;                       // unrounded f32 (closer to ref)
        unsigned int pk = (unsigned int)f2bf(p0) | ((unsigned int)f2bf(p1) << 16);
        *(unsigned int*)&Pw[(s*16 + quad*4 + r) * 40 + 2*l16] = pk;
      }
    }

    // ---- PV: P A-frags from own LDS; V B-frags direct from global (L2) ----
    bf16x8 pfr0 = *(const bf16x8*)&Pw[(l16) * 40 + quad*8];
    bf16x8 pfr1 = *(const bf16x8*)&Pw[(16 + l16) * 40 + quad*8];
    bf16x8 vf[8];
#pragma unroll
    for (int dt = 0; dt < 8; ++dt)
      vf[dt] = *(const bf16x8*)(whT_b + (size_t)(dt*16 + l16) * NN + m0 + ms*32 + quad*8);
    __builtin_amdgcn_s_setprio(1);
#pragma unroll
    for (int dt = 0; dt < 8; ++dt){
      oacc[0][dt] = __builtin_amdgcn_mfma_f32_16x16x32_bf16(pfr0, vf[dt], oacc[0][dt], 0, 0, 0);
      oacc[1][dt] = __builtin_amdgcn_mfma_f32_16x16x32_bf16(pfr1, vf[dt], oacc[1][dt], 0, 0, 0);
    }
    __builtin_amdgcn_s_setprio(0);

#pragma unroll
    for (int s = 0; s < 2; ++s)
#pragma unroll
      for (int r = 0; r < 4; ++r)
        av[s][r] = avn[s][r];
  }

  __syncthreads();   // all waves done with their Pw before fl overlays the region

  // ---- l reduction: fl[qrow64][ms*16+l16] in smem (16 KB) ----
  {
    float* fl = smem;
#pragma unroll
    for (int s = 0; s < 2; ++s)
#pragma unroll
      for (int r = 0; r < 4; ++r)
        fl[(qh*32 + s*16 + quad*4 + r) * 64 + ms*16 + l16] = lacc[s][r];
  }
  __syncthreads();
  if (t < 64){
    const float* fl = smem;
    float sum = 0.f;
#pragma unroll
    for (int c = 0; c < 64; ++c) sum += fl[t * 64 + c];
    linv_s[t] = 1.0f / sum;
  }

  // ---- output: reduce oacc across the 4 m-strips per q-half (smem as owf) ----
  float* const owf = smem;    // 64 KB: [wave][16 rows][128 d]
  for (int s = 0; s < 2; ++s){
    __syncthreads();
#pragma unroll
    for (int dt = 0; dt < 8; ++dt)
#pragma unroll
      for (int r = 0; r < 4; ++r)
        owf[w*2048 + (quad*4 + r)*128 + dt*16 + l16] = oacc[s][dt][r];
    __syncthreads();
#pragma unroll
    for (int j = 0; j < 8; ++j){
      const int o     = j*512 + t;
      const int row32 = o >> 7;
      const int d     = o & 127;
      const int qh2   = row32 >> 4;
      const int r16   = row32 & 15;
      float v = owf[(qh2*4 + 0)*2048 + r16*128 + d]
              + owf[(qh2*4 + 1)*2048 + r16*128 + d]
              + owf[(qh2*4 + 2)*2048 + r16*128 + d]
              + owf[(qh2*4 + 3)*2048 + r16*128 + d];
      const int qrl = qh2*32 + s*16 + r16;
      v *= linv_s[qrl];
      v = (v > 0.f) ? v : expm1f(v);        // ELU (alpha=1)
      out[(size_t)(b*NN + qbase + qrl) * DD + d] = v;
    }
  }
}

extern "C" void kernel_launch(void* const* d_in, const int* in_sizes, int n_in,
                              void* d_out, int out_size, void* d_ws, size_t ws_size,
                              hipStream_t stream)
{
  const float* h       = (const float*)d_in[0];
  // d_in[1] = adj  (unused by the reference)
  const int*   adj_eye = (const int*)d_in[2];
  const float* W       = (const float*)d_in[3];
  float*       out     = (float*)d_out;

  unsigned short* whn  = (unsigned short*)d_ws;                   // 16384*128 bf16 = 4 MB
  unsigned short* whT  = whn + (size_t)16384 * 128;               // 8*128*2048 bf16 = 4 MB

  wh_kernel<<<512, 256, 0, stream>>>(h, W, whn, whT);
  attn_kernel<<<256, 512, 0, stream>>>(whn, whT, adj_eye, out);
}